// Round 1
// 5106.926 us; speedup vs baseline: 1.0527x; 1.0527x over previous
//
#include <hip/hip_runtime.h>
#include <hip/hip_bf16.h>

typedef __attribute__((ext_vector_type(8))) short  bf16x8;
typedef __attribute__((ext_vector_type(4))) float  f32x4;
typedef __attribute__((ext_vector_type(4))) unsigned int u32x4;

#define EOS 2
#define S 1024
#define B 64
#define E 256
#define H 512
#define SENT 0xFFFFFFFFu

// ws layout:
//   [0, 32)               per-XCD arrival counters (8 x int, zeroed)
//   [32, 36)              winner XCD id (int, init -1)
//   [4096, 4096+512K)     hbuf: 4 slots x {hi,lo} x [64][512] bf16
//                         slot0 = 0 (h0), slots1-3 = 0xFF (sentinel)
//   [528384, 593920)      dest8 map [1024][64] int8
#define HBUF_OFF 4096
#define SLOT (2 * B * H)              // shorts per slot (hi+lo)
#define DEST_OFF (HBUF_OFF + 4 * SLOT * 2)

// Same-XCD edition: all cross-WG h traffic stays in the winner XCD's L2.
// Stores are plain (write-through L1 -> L2, workgroup-scope atomic so the
// compiler can't elide/reorder); polls are sc0 loads (L1-bypass, L2-hit).
#define AT_ST(p, v) __hip_atomic_store((p), (v), __ATOMIC_RELAXED, __HIP_MEMORY_SCOPE_WORKGROUP)

__device__ __forceinline__ unsigned short f2bf(float f) {
    unsigned int u = __builtin_bit_cast(unsigned int, f);
    unsigned int r = (u + 0x7FFFu + ((u >> 16) & 1u)) >> 16;
    return (unsigned short)r;
}
__device__ __forceinline__ float bf2f(unsigned short s) {
    unsigned int u = ((unsigned int)s) << 16;
    return __builtin_bit_cast(float, u);
}
__device__ __forceinline__ unsigned int pk2(float x, float y) {  // round-half-up pair
    unsigned int ux = __builtin_bit_cast(unsigned int, x) + 0x8000u;
    unsigned int uy = __builtin_bit_cast(unsigned int, y) + 0x8000u;
    return (ux >> 16) | (uy & 0xFFFF0000u);
}
__device__ __forceinline__ bf16x8 pack8hu(float4 a, float4 b) {
    union { unsigned int d[4]; bf16x8 v; } u;
    u.d[0] = pk2(a.x, a.y); u.d[1] = pk2(a.z, a.w);
    u.d[2] = pk2(b.x, b.y); u.d[3] = pk2(b.z, b.w);
    return u.v;
}
__device__ __forceinline__ bf16x8 pack8rne(float4 a, float4 b) {
    union { unsigned short s[8]; bf16x8 v; } u;
    u.s[0] = f2bf(a.x); u.s[1] = f2bf(a.y); u.s[2] = f2bf(a.z); u.s[3] = f2bf(a.w);
    u.s[4] = f2bf(b.x); u.s[5] = f2bf(b.y); u.s[6] = f2bf(b.z); u.s[7] = f2bf(b.w);
    return u.v;
}

// ---------------------------------------------------------------------------
// dest8[t][b] = k-th EOS index (0..31) or -1, int8
// ---------------------------------------------------------------------------
__global__ __launch_bounds__(256) void dest_kernel(const int* __restrict__ tokens,
                                                   signed char* __restrict__ dest8) {
    const int b = blockIdx.x, tid = threadIdx.x;
    const int l = tid & 63, w = tid >> 6;
    const int base = tid * 4;
    int m[4], cnt = 0;
#pragma unroll
    for (int i = 0; i < 4; ++i) {
        int tok = tokens[b * S + base + i];
        m[i] = (tok == EOS) ? 1 : 0;
        cnt += m[i];
    }
    int inc = cnt;
#pragma unroll
    for (int d = 1; d < 64; d <<= 1) {
        int v = __shfl_up(inc, d, 64);
        if (l >= d) inc += v;
    }
    __shared__ int wt[4];
    if (l == 63) wt[w] = inc;
    __syncthreads();
    int off = 0;
    for (int k = 0; k < 4; ++k)
        if (k < w) off += wt[k];
    int run = off + inc - cnt;  // exclusive prefix
#pragma unroll
    for (int i = 0; i < 4; ++i) {
        dest8[(base + i) * B + b] = m[i] ? (signed char)run : (signed char)-1;
        run += m[i];
    }
}

// ---------------------------------------------------------------------------
// Persistent fused GRU, sentinel-sync, SAME-XCD edition.
// Launch 256 WGs; each reads HW_REG_XCC_ID, takes an agent-scope per-XCD
// ticket; first XCD to reach 32 arrivals wins (pigeonhole over 256 WGs / 8
// XCDs guarantees one exists; all 256 WGs are co-resident at 256 VGPR).
// The 32 winner-XCD ticket holders become workers (slot = ticket); the rest
// exit. All h-slot traffic then stays in the winner XCD's L2: plain
// write-through stores publish, sc0 loads poll -- the cross-XCD L3 round
// trips of the previous round (sc1 stores + sc1 polls) collapse to L2 RTTs.
// Compute core / slot rotation / re-sentinel scheme / numerics unchanged;
// the skew<=1 reuse proof is scope-independent and carries over.
// ---------------------------------------------------------------------------
__global__ __launch_bounds__(256, 1) void gru_kernel(
    const int* __restrict__ tokens, const float* __restrict__ emb,
    const float* __restrict__ w_ih, const float* __restrict__ w_hh,
    const float* __restrict__ b_ih, const float* __restrict__ b_hh,
    const signed char* __restrict__ dest8,
    char* ws, float* __restrict__ out) {

    // ---- XCD claim protocol (thread 0, broadcast via LDS) ----
    __shared__ int s_slot;
    if (threadIdx.x == 0) {
        unsigned int xcc;
        asm volatile("s_getreg_b32 %0, hwreg(HW_REG_XCC_ID)" : "=s"(xcc));
        xcc &= 7u;
        int* cnt = (int*)ws;
        int* win = (int*)(ws + 32);
        int ticket = __hip_atomic_fetch_add(&cnt[xcc], 1, __ATOMIC_RELAXED,
                                            __HIP_MEMORY_SCOPE_AGENT);
        int slot = -1;
        if (ticket < 32) {
            if (ticket == 31) {   // 32nd arrival on this XCD: try to claim win
                int exp = -1;
                __hip_atomic_compare_exchange_strong(win, &exp, (int)xcc,
                    __ATOMIC_RELAXED, __ATOMIC_RELAXED, __HIP_MEMORY_SCOPE_AGENT);
            }
            int wv = -1, bud = 1 << 18;
            do {
                wv = __hip_atomic_load(win, __ATOMIC_RELAXED,
                                       __HIP_MEMORY_SCOPE_AGENT);
            } while (wv == -1 && --bud > 0);
            if (wv == -1) {       // pathological timeout: force a decision
                int exp = -1;
                __hip_atomic_compare_exchange_strong(win, &exp, (int)xcc,
                    __ATOMIC_RELAXED, __ATOMIC_RELAXED, __HIP_MEMORY_SCOPE_AGENT);
                wv = __hip_atomic_load(win, __ATOMIC_RELAXED,
                                       __HIP_MEMORY_SCOPE_AGENT);
            }
            if (wv == (int)xcc) slot = ticket;
        }
        s_slot = slot;
    }
    __syncthreads();
    const int blk = s_slot;
    if (blk < 0) return;                 // not a worker

    const int tid = threadIdx.x;         // 0..255
    const int wv = tid >> 6;             // wave in WG (0..3)
    const int l = tid & 63;
    const int l15 = l & 15, quad = l >> 4;
    const int w = blk & 3;               // batch slice
    const int j4 = blk >> 2;             // unit-group quad (0..7)
    const int unit = (j4 * 4 + wv) * 16 + l15;
    const int koff = quad * 8;
    const int brow = w * 16 + l15;

    unsigned short* hbuf = (unsigned short*)(ws + HBUF_OFF);

    __shared__ alignas(16) unsigned short sh[2][16][512];  // {hi,lo} x rows x units, XOR-swizzled

    // ---- one-time: weight B-fragments into registers (RNE bf16) ----
    bf16x8 Wh[3][16];
#pragma unroll
    for (int g = 0; g < 3; ++g)
#pragma unroll
        for (int kt = 0; kt < 16; ++kt) {
            const float* p = &w_hh[(size_t)(g * H + unit) * H + kt * 32 + koff];
            Wh[g][kt] = pack8rne(*(const float4*)p, *(const float4*)(p + 4));
        }
    bf16x8 Wi[3][8];
#pragma unroll
    for (int g = 0; g < 3; ++g)
#pragma unroll
        for (int kt = 0; kt < 8; ++kt) {
            const float* p = &w_ih[(size_t)(g * H + unit) * E + kt * 32 + koff];
            Wi[g][kt] = pack8rne(*(const float4*)p, *(const float4*)(p + 4));
        }
    const float bi0 = b_ih[unit], bi1 = b_ih[H + unit], bi2 = b_ih[2 * H + unit];
    const float bh0 = b_hh[unit], bh1 = b_hh[H + unit], bh2 = b_hh[2 * H + unit];

    float hown[4] = {0.f, 0.f, 0.f, 0.f};
    int tok_next = tokens[brow * S];
    int budget = 1 << 21;                // anti-hang safety (total poll iters)

    // staging map: thread -> (plane, row, 16B chunk column), chunks strided
    // 128B so each load instruction is 128B-coalesced across 8 lanes.
    const int p_st  = tid >> 7;          // 0..1 (hi/lo plane)
    const int rr_st = (tid >> 3) & 15;   // row 0..15
    const int t7    = tid & 7;           // 16B sub-column

    for (int t = 0; t < S; ++t) {
        // --- independent work first (overlaps the data poll) ---
        const int tok = tok_next;
        const float* er = &emb[(size_t)tok * E + koff];
        float4 ef[8][2];
#pragma unroll
        for (int kt = 0; kt < 8; ++kt) {
            ef[kt][0] = *(const float4*)(er + kt * 32);
            ef[kt][1] = *(const float4*)(er + kt * 32 + 4);
        }
        if (t + 1 < S) tok_next = tokens[brow * S + t + 1];
        unsigned int dword =
            *(const unsigned int*)&dest8[t * B + w * 16 + quad * 4];

        f32x4 gi0 = {bi0, bi0, bi0, bi0};
        f32x4 gi1 = {bi1, bi1, bi1, bi1};
        f32x4 gi2 = {bi2, bi2, bi2, bi2};
#pragma unroll
        for (int kt = 0; kt < 8; ++kt) {
            bf16x8 af = pack8hu(ef[kt][0], ef[kt][1]);
            gi0 = __builtin_amdgcn_mfma_f32_16x16x32_bf16(af, Wi[0][kt], gi0, 0, 0, 0);
            gi1 = __builtin_amdgcn_mfma_f32_16x16x32_bf16(af, Wi[1][kt], gi1, 0, 0, 0);
            gi2 = __builtin_amdgcn_mfma_f32_16x16x32_bf16(af, Wi[2][kt], gi2, 0, 0, 0);
        }

        // --- cooperative stage WITH sentinel poll: data IS the ready flag.
        //     sc0 = L1-bypass, served from the (shared, same-XCD) L2. ---
        {
            const unsigned short* hs = hbuf + (size_t)(t & 3) * SLOT;
            const unsigned short* gp =
                hs + (size_t)p_st * (B * H) + (size_t)(w * 16 + rr_st) * H + t7 * 8;
            u32x4 gr[8];
            unsigned int bad;
            do {
                asm volatile(
                    "global_load_dwordx4 %0, %8, off sc0\n\t"
                    "global_load_dwordx4 %1, %8, off offset:128 sc0\n\t"
                    "global_load_dwordx4 %2, %8, off offset:256 sc0\n\t"
                    "global_load_dwordx4 %3, %8, off offset:384 sc0\n\t"
                    "global_load_dwordx4 %4, %8, off offset:512 sc0\n\t"
                    "global_load_dwordx4 %5, %8, off offset:640 sc0\n\t"
                    "global_load_dwordx4 %6, %8, off offset:768 sc0\n\t"
                    "global_load_dwordx4 %7, %8, off offset:896 sc0\n\t"
                    "s_waitcnt vmcnt(0)"
                    : "=&v"(gr[0]), "=&v"(gr[1]), "=&v"(gr[2]), "=&v"(gr[3]),
                      "=&v"(gr[4]), "=&v"(gr[5]), "=&v"(gr[6]), "=&v"(gr[7])
                    : "v"(gp)
                    : "memory");
                bad = 0;
#pragma unroll
                for (int c = 0; c < 8; ++c)
                    bad |= (unsigned)((gr[c][0] == SENT) | (gr[c][1] == SENT) |
                                      (gr[c][2] == SENT) | (gr[c][3] == SENT));
            } while (bad && --budget > 0);
            // XOR-swizzled LDS placement: chunk index c8 = t7 + 8*c
#pragma unroll
            for (int c = 0; c < 8; ++c) {
                int pos = ((t7 + 8 * c) ^ (rr_st & 7)) * 8;
                *(u32x4*)&sh[p_st][rr_st][pos] = gr[c];
            }
        }

        // --- re-sentinel own write region of slot (t+2)%4 (drain is later,
        //     hidden under the MFMA chain) ---
        {
            unsigned short* rs = hbuf + (size_t)((t + 2) & 3) * SLOT;
            const size_t rbase = (size_t)(w * 16 + (tid >> 4)) * H + j4 * 64;
            unsigned int* ph = (unsigned int*)(rs + rbase) + (tid & 15) * 2;
            unsigned int* pl = (unsigned int*)(rs + B * H + rbase) + (tid & 15) * 2;
            AT_ST(ph, SENT); AT_ST(ph + 1, SENT);
            AT_ST(pl, SENT); AT_ST(pl + 1, SENT);
        }
        __syncthreads();   // stage complete -> frags readable

        // --- gh = b_hh + h . W_hh^T (bf16 hi+lo split) from swizzled LDS ---
        f32x4 a0 = {bh0, bh0, bh0, bh0};
        f32x4 a1 = {bh1, bh1, bh1, bh1};
        f32x4 a2 = {bh2, bh2, bh2, bh2};
#pragma unroll
        for (int kt = 0; kt < 16; ++kt) {
            const int pos = ((kt * 4 + quad) ^ (l15 & 7)) * 8;
            bf16x8 ah = *(const bf16x8*)&sh[0][l15][pos];
            bf16x8 al = *(const bf16x8*)&sh[1][l15][pos];
            a0 = __builtin_amdgcn_mfma_f32_16x16x32_bf16(ah, Wh[0][kt], a0, 0, 0, 0);
            a1 = __builtin_amdgcn_mfma_f32_16x16x32_bf16(ah, Wh[1][kt], a1, 0, 0, 0);
            a2 = __builtin_amdgcn_mfma_f32_16x16x32_bf16(ah, Wh[2][kt], a2, 0, 0, 0);
            a0 = __builtin_amdgcn_mfma_f32_16x16x32_bf16(al, Wh[0][kt], a0, 0, 0, 0);
            a1 = __builtin_amdgcn_mfma_f32_16x16x32_bf16(al, Wh[1][kt], a1, 0, 0, 0);
            a2 = __builtin_amdgcn_mfma_f32_16x16x32_bf16(al, Wh[2][kt], a2, 0, 0, 0);
        }

        // --- gates ---
        float hval[4];
        unsigned int pkv[4];
#pragma unroll
        for (int r = 0; r < 4; ++r) {
            float rg = 1.f / (1.f + __expf(-(gi0[r] + a0[r])));
            float zg = 1.f / (1.f + __expf(-(gi1[r] + a1[r])));
            float x = gi2[r] + rg * a2[r];
            x = fminf(15.f, fmaxf(-15.f, x));
            float e = __expf(-2.f * x);
            float ng = (1.f - e) / (1.f + e);
            float h = (1.f - zg) * ng + zg * hown[r];   // fp32 carry (exact)
            hown[r] = h; hval[r] = h;
            unsigned short hi16 = f2bf(h);
            unsigned short lo16 = f2bf(h - bf2f(hi16));
            pkv[r] = ((unsigned int)lo16 << 16) | (unsigned int)hi16;
        }

        // --- drain (resets + stage loads; mostly already landed), then
        //     publish h[t+1]: the stores themselves are the ready signal ---
        asm volatile("s_waitcnt vmcnt(0)" ::: "memory");
        {
            unsigned short* hd = hbuf + (size_t)((t + 1) & 3) * SLOT;
            unsigned int* hd_hi32 = (unsigned int*)hd;
            unsigned int* hd_lo32 = (unsigned int*)(hd + B * H);
            const bool even = (l15 & 1) == 0;
#pragma unroll
            for (int r = 0; r < 4; ++r) {
                const int b = w * 16 + quad * 4 + r;
                unsigned int sw = (unsigned int)__shfl_xor((int)pkv[r], 1);
                unsigned int val = even ? ((pkv[r] & 0xFFFFu) | (sw << 16))
                                        : ((sw >> 16) | (pkv[r] & 0xFFFF0000u));
                unsigned int didx = ((unsigned int)(b * H + unit)) >> 1;
                AT_ST((even ? hd_hi32 : hd_lo32) + didx, val);
            }
        }
        __syncthreads();   // all waves done reading sh -> next stage may write

        // --- out writes AFTER publish (off the critical chain) ---
#pragma unroll
        for (int r = 0; r < 4; ++r) {
            const int b = w * 16 + quad * 4 + r;
            int db = (int)(signed char)((dword >> (8 * r)) & 0xFFu);
            if (db >= 0)
                out[((size_t)(db * B + b)) * H + unit] = hval[r];
        }
    }
}

extern "C" void kernel_launch(void* const* d_in, const int* in_sizes, int n_in,
                              void* d_out, int out_size, void* d_ws, size_t ws_size,
                              hipStream_t stream) {
    const int*   tokens = (const int*)d_in[0];
    const float* emb    = (const float*)d_in[1];
    const float* w_ih   = (const float*)d_in[2];
    const float* w_hh   = (const float*)d_in[3];
    const float* b_ih   = (const float*)d_in[4];
    const float* b_hh   = (const float*)d_in[5];
    float* out = (float*)d_out;

    char* ws = (char*)d_ws;
    signed char* dest8 = (signed char*)(ws + DEST_OFF);

    // control block: per-XCD counters = 0, winner = -1
    hipMemsetAsync(ws, 0, 32, stream);
    hipMemsetAsync(ws + 32, 0xFF, 4, stream);
    // slot0 = zeros (h0, immediately valid); slots 1-3 = sentinel 0xFF bytes
    hipMemsetAsync(ws + HBUF_OFF, 0, SLOT * 2, stream);
    hipMemsetAsync(ws + HBUF_OFF + SLOT * 2, 0xFF, 3 * SLOT * 2, stream);
    dest_kernel<<<B, 256, 0, stream>>>(tokens, dest8);
    gru_kernel<<<256, 256, 0, stream>>>(tokens, emb, w_ih, w_hh, b_ih, b_hh,
                                        dest8, ws, out);
}